// Round 11
// baseline (490.443 us; speedup 1.0000x reference)
//
#include <hip/hip_runtime.h>
#include <hip/hip_bf16.h>
#include <stdint.h>

#define DM   1024
#define SJ   4608
#define SCTX 512
#define SIMG 4096
#define NCH  512
#define TCH  9

typedef __attribute__((ext_vector_type(4)))  int   i32x4;
typedef __attribute__((ext_vector_type(16))) int   i32x16;
typedef __attribute__((ext_vector_type(4)))  float f32x4;

__device__ __forceinline__ float bf2f(unsigned short u){
  union { unsigned int i; float f; } v; v.i = ((unsigned int)u) << 16; return v.f;
}
__device__ __forceinline__ unsigned short f2bf(float f){
  unsigned int u = __float_as_uint(f);
  u += 0x7fffu + ((u >> 16) & 1u);
  return (unsigned short)(u >> 16);
}
__device__ __forceinline__ float sigm(float x){ return 1.f/(1.f+__expf(-x)); }
__device__ __forceinline__ signed char q8(float v, float lo, float hi){
  return (signed char)(int)fminf(fmaxf(rintf(v),lo),hi);
}

__device__ __forceinline__ float wsum(float v){
  #pragma unroll
  for(int o=32;o>0;o>>=1) v += __shfl_xor(v,o);
  return v;
}
__device__ __forceinline__ float wmax(float v){
  #pragma unroll
  for(int o=32;o>0;o>>=1) v = fmaxf(v,__shfl_xor(v,o));
  return v;
}
__device__ __forceinline__ void blockSumSum(float& a, float& b, float* s1, float* s2){
  a = wsum(a); b = wsum(b);
  if(!(threadIdx.x&63)){ s1[threadIdx.x>>6]=a; s2[threadIdx.x>>6]=b; }
  __syncthreads();
  a = s1[0]+s1[1]+s1[2]+s1[3];
  b = s2[0]+s2[1]+s2[2]+s2[3];
  __syncthreads();
}
__device__ __forceinline__ void blockSumMax(float& a, float& b, float* s1, float* s2){
  a = wsum(a); b = wmax(b);
  if(!(threadIdx.x&63)){ s1[threadIdx.x>>6]=a; s2[threadIdx.x>>6]=b; }
  __syncthreads();
  a = s1[0]+s1[1]+s1[2]+s1[3];
  b = fmaxf(fmaxf(s2[0],s2[1]),fmaxf(s2[2],s2[3]));
  __syncthreads();
}

// ---------------- async global->LDS ----------------
typedef __attribute__((address_space(1))) void gvoid_t;
typedef __attribute__((address_space(3))) void lvoid_t;
__device__ __forceinline__ void gl_lds16(const void* g, void* l){
  __builtin_amdgcn_global_load_lds((gvoid_t*)g, (lvoid_t*)l, 16, 0, 0);
}

// ---------------- weight quantization ----------------
struct WList {
  const float* w[8];
  unsigned long long n[8];
  signed char* q[8];
};

__global__ __launch_bounds__(256)
void wq_reduce(WList L, float* __restrict__ part){
  __shared__ float s1[4];
  int m = blockIdx.y;
  const float4* w4 = (const float4*)L.w[m];
  size_t n4 = L.n[m] >> 2;
  float s = 0.f;
  for(size_t i = (size_t)blockIdx.x*256 + threadIdx.x; i < n4; i += (size_t)512*256){
    float4 v = w4[i];
    s += fabsf(v.x)+fabsf(v.y)+fabsf(v.z)+fabsf(v.w);
  }
  s = wsum(s);
  if(!(threadIdx.x&63)) s1[threadIdx.x>>6] = s;
  __syncthreads();
  if(!threadIdx.x) part[m*512 + blockIdx.x] = s1[0]+s1[1]+s1[2]+s1[3];
}

__global__ __launch_bounds__(256)
void wq_finalize(WList L, const float* __restrict__ part, float* __restrict__ swinv){
  __shared__ float s1[4];
  int m = blockIdx.x;
  float s = part[m*512 + threadIdx.x] + part[m*512 + 256 + threadIdx.x];
  s = wsum(s);
  if(!(threadIdx.x&63)) s1[threadIdx.x>>6] = s;
  __syncthreads();
  if(!threadIdx.x){
    float mean = (s1[0]+s1[1]+s1[2]+s1[3]) / (float)L.n[m];
    swinv[m] = fmaxf(mean, 1e-5f);
  }
}

__global__ __launch_bounds__(256)
void wq_quant(WList L, const float* __restrict__ swinv){
  int m = blockIdx.y;
  float sc = 1.f / swinv[m];
  const float4* w4 = (const float4*)L.w[m];
  signed char* q = L.q[m];
  size_t n4 = L.n[m] >> 2;
  for(size_t i = (size_t)blockIdx.x*256 + threadIdx.x; i < n4; i += (size_t)1024*256){
    float4 v = w4[i];
    char4 o;
    o.x = q8(v.x*sc,-1.f,1.f);
    o.y = q8(v.y*sc,-1.f,1.f);
    o.z = q8(v.z*sc,-1.f,1.f);
    o.w = q8(v.w*sc,-1.f,1.f);
    ((char4*)q)[i] = o;
  }
}

// ---------------- adaLN embedding GEMV ----------------
__global__ __launch_bounds__(256)
void adaln_gemv(const float* __restrict__ temb, const float* __restrict__ W,
                const float* __restrict__ bias, float* __restrict__ e){
  int o = blockIdx.x*4 + (threadIdx.x>>6);
  int b = blockIdx.y;
  int lane = threadIdx.x & 63;
  const float4* t4 = (const float4*)(temb + b*DM);
  const float4* w4 = (const float4*)(W + (size_t)o*DM);
  float acc = 0.f;
  #pragma unroll
  for(int i=0;i<4;i++){
    float4 tv = t4[i*64+lane], wv = w4[i*64+lane];
    acc += (tv.x*sigm(tv.x))*wv.x + (tv.y*sigm(tv.y))*wv.y
         + (tv.z*sigm(tv.z))*wv.z + (tv.w*sigm(tv.w))*wv.w;
  }
  acc = wsum(acc);
  if(!lane) e[b*6144 + o] = acc + bias[o];
}

// ---------------- LN -> adaLN modulate -> rmsnorm -> act_quant (int8) ----------------
__global__ __launch_bounds__(256)
void modnorm_quant(const float* __restrict__ x, int bshift,
                   const float* __restrict__ e, int scaleOff, int shiftOff,
                   signed char* __restrict__ xq, float* __restrict__ rsx,
                   int outRowOff, int outBatchStride){
  __shared__ float s1[4], s2[4];
  const int tid = threadIdx.x;
  const int row = blockIdx.x;
  const int b = row >> bshift, s = row & ((1<<bshift)-1);
  float4 xv = ((const float4*)(x + (size_t)row*DM))[tid];
  float sum = xv.x+xv.y+xv.z+xv.w;
  float ss  = xv.x*xv.x+xv.y*xv.y+xv.z*xv.z+xv.w*xv.w;
  blockSumSum(sum, ss, s1, s2);
  float mu  = sum * (1.f/DM);
  float inv = rsqrtf(ss*(1.f/DM) - mu*mu + 1e-6f);
  float4 scv = ((const float4*)(e + b*6144 + scaleOff))[tid];
  float4 shv = ((const float4*)(e + b*6144 + shiftOff))[tid];
  float n0 = (xv.x-mu)*inv*(1.f+scv.x)+shv.x;
  float n1 = (xv.y-mu)*inv*(1.f+scv.y)+shv.y;
  float n2 = (xv.z-mu)*inv*(1.f+scv.z)+shv.z;
  float n3 = (xv.w-mu)*inv*(1.f+scv.w)+shv.w;
  float ss2 = n0*n0+n1*n1+n2*n2+n3*n3;
  float mx  = fmaxf(fmaxf(fabsf(n0),fabsf(n1)),fmaxf(fabsf(n2),fabsf(n3)));
  blockSumMax(ss2, mx, s1, s2);
  float rms   = rsqrtf(ss2*(1.f/DM) + 1e-6f);
  float amaxn = fmaxf(mx*rms, 1e-5f);
  float k     = rms*127.f/amaxn;
  int orow = b*outBatchStride + outRowOff + s;
  char4 q;
  q.x = q8(n0*k,-128.f,127.f);
  q.y = q8(n1*k,-128.f,127.f);
  q.z = q8(n2*k,-128.f,127.f);
  q.w = q8(n3*k,-128.f,127.f);
  ((char4*)(xq + (size_t)orow*DM))[tid] = q;
  if(!tid) rsx[orow] = amaxn*(1.f/127.f);
}

// ---- fused: hnew = x + gate*attn ; write hnew ; LN->mod->rmsnorm->quant ----
__global__ __launch_bounds__(256)
void resid_modnorm(const float* __restrict__ x, const unsigned short* __restrict__ attn,
                   int attnRowOff, int bshift,
                   const float* __restrict__ e,
                   float* __restrict__ hout,
                   signed char* __restrict__ xq, float* __restrict__ rsx){
  __shared__ float s1[4], s2[4];
  const int tid = threadIdx.x;
  const int row = blockIdx.x;
  const int b = row >> bshift, s = row & ((1<<bshift)-1);
  const int arow = b*SJ + attnRowOff + s;
  float4 xv = ((const float4*)(x + (size_t)row*DM))[tid];
  ushort4 av = ((const ushort4*)(attn + (size_t)arow*DM))[tid];
  float4 gv = ((const float4*)(e + b*6144 + 2*1024))[tid];
  float h0 = xv.x + gv.x*bf2f(av.x);
  float h1 = xv.y + gv.y*bf2f(av.y);
  float h2 = xv.z + gv.z*bf2f(av.z);
  float h3 = xv.w + gv.w*bf2f(av.w);
  ((float4*)(hout + (size_t)row*DM))[tid] = make_float4(h0,h1,h2,h3);
  float sum = h0+h1+h2+h3;
  float ss  = h0*h0+h1*h1+h2*h2+h3*h3;
  blockSumSum(sum, ss, s1, s2);
  float mu  = sum * (1.f/DM);
  float inv = rsqrtf(ss*(1.f/DM) - mu*mu + 1e-6f);
  float4 scv = ((const float4*)(e + b*6144 + 3*1024))[tid];
  float4 shv = ((const float4*)(e + b*6144 + 4*1024))[tid];
  float n0 = (h0-mu)*inv*(1.f+scv.x)+shv.x;
  float n1 = (h1-mu)*inv*(1.f+scv.y)+shv.y;
  float n2 = (h2-mu)*inv*(1.f+scv.z)+shv.z;
  float n3 = (h3-mu)*inv*(1.f+scv.w)+shv.w;
  float ss2 = n0*n0+n1*n1+n2*n2+n3*n3;
  float mx  = fmaxf(fmaxf(fabsf(n0),fabsf(n1)),fmaxf(fabsf(n2),fabsf(n3)));
  blockSumMax(ss2, mx, s1, s2);
  float rms   = rsqrtf(ss2*(1.f/DM) + 1e-6f);
  float amaxn = fmaxf(mx*rms, 1e-5f);
  float k     = rms*127.f/amaxn;
  char4 q;
  q.x = q8(n0*k,-128.f,127.f);
  q.y = q8(n1*k,-128.f,127.f);
  q.z = q8(n2*k,-128.f,127.f);
  q.w = q8(n3*k,-128.f,127.f);
  ((char4*)(xq + (size_t)row*DM))[tid] = q;
  if(!tid) rsx[row] = amaxn*(1.f/127.f);
}

// ---- out = hnew + gate(chunk5)*mlp ----
__global__ __launch_bounds__(256)
void resid_out(const float* __restrict__ hnew, const unsigned short* __restrict__ mlp,
               const float* __restrict__ e, int bshift, float* __restrict__ out){
  const int tid = threadIdx.x;
  const int row = blockIdx.x;
  const int b = row >> bshift;
  float4 hv = ((const float4*)(hnew + (size_t)row*DM))[tid];
  ushort4 mv = ((const ushort4*)(mlp + (size_t)row*DM))[tid];
  float4 gv = ((const float4*)(e + b*6144 + 5*1024))[tid];
  float4 o;
  o.x = hv.x + gv.x*bf2f(mv.x);
  o.y = hv.y + gv.y*bf2f(mv.y);
  o.z = hv.z + gv.z*bf2f(mv.z);
  o.w = hv.w + gv.w*bf2f(mv.w);
  ((float4*)(out + (size_t)row*DM))[tid] = o;
}

// ---------------- rmsnorm -> act_quant, bf16 D=4096 rows -> int8 ----------------
__global__ __launch_bounds__(256)
void rmsq4096(const unsigned short* __restrict__ z, signed char* __restrict__ zq,
              float* __restrict__ rsx){
  __shared__ float s1[4], s2[4];
  const int tid = threadIdx.x;
  const unsigned short* zr = z + (size_t)blockIdx.x*4096;
  signed char* qr = zq + (size_t)blockIdx.x*4096;
  float v[16];
  #pragma unroll
  for(int i=0;i<4;i++){
    ushort4 u = ((const ushort4*)zr)[tid + i*256];
    v[i*4+0]=bf2f(u.x); v[i*4+1]=bf2f(u.y); v[i*4+2]=bf2f(u.z); v[i*4+3]=bf2f(u.w);
  }
  float ss=0.f, mx=0.f;
  #pragma unroll
  for(int i=0;i<16;i++){ ss += v[i]*v[i]; mx = fmaxf(mx, fabsf(v[i])); }
  blockSumMax(ss, mx, s1, s2);
  float rms   = rsqrtf(ss*(1.f/4096.f) + 1e-6f);
  float amaxn = fmaxf(mx*rms, 1e-5f);
  float k     = rms*127.f/amaxn;
  #pragma unroll
  for(int i=0;i<4;i++){
    char4 q;
    q.x = q8(v[i*4+0]*k,-128.f,127.f);
    q.y = q8(v[i*4+1]*k,-128.f,127.f);
    q.z = q8(v[i*4+2]*k,-128.f,127.f);
    q.w = q8(v[i*4+3]*k,-128.f,127.f);
    ((char4*)qr)[tid + i*256] = q;
  }
  if(!tid) rsx[blockIdx.x] = amaxn*(1.f/127.f);
}

// ---------------- HGRN chunked scan ----------------
__global__ __launch_bounds__(256)
void scan_pass1(const unsigned short* __restrict__ ir, const unsigned short* __restrict__ fr,
                float* __restrict__ A, float* __restrict__ B){
  int c = blockIdx.x, b = blockIdx.y;
  int d0 = threadIdx.x*4;
  size_t base = ((size_t)b*SJ + (size_t)c*TCH)*DM + d0;
  float a0=1,a1=1,a2=1,a3=1, h0=0,h1=0,h2=0,h3=0;
  #pragma unroll
  for(int t=0;t<TCH;t++){
    ushort4 iv = *(const ushort4*)(ir + base + (size_t)t*DM);
    ushort4 fv = *(const ushort4*)(fr + base + (size_t)t*DM);
    float f0=sigm(bf2f(fv.x)), f1=sigm(bf2f(fv.y)), f2=sigm(bf2f(fv.z)), f3=sigm(bf2f(fv.w));
    float x0=bf2f(iv.x), x1=bf2f(iv.y), x2=bf2f(iv.z), x3=bf2f(iv.w);
    float p0=x0*sigm(x0)*(1.f-f0), p1=x1*sigm(x1)*(1.f-f1);
    float p2=x2*sigm(x2)*(1.f-f2), p3=x3*sigm(x3)*(1.f-f3);
    h0=f0*h0+p0; h1=f1*h1+p1; h2=f2*h2+p2; h3=f3*h3+p3;
    a0*=f0; a1*=f1; a2*=f2; a3*=f3;
  }
  size_t idx = (size_t)c*2048 + b*1024 + d0;
  *(float4*)(A + idx) = make_float4(a0,a1,a2,a3);
  *(float4*)(B + idx) = make_float4(h0,h1,h2,h3);
}

__global__ __launch_bounds__(256)
void scan_pass2(const float* __restrict__ A, const float* __restrict__ B, float* __restrict__ H){
  int chain = blockIdx.x*256 + threadIdx.x;
  float h = 0.f;
  for(int c0=0;c0<NCH;c0+=8){
    float a[8], bb[8];
    #pragma unroll
    for(int u=0;u<8;u++){
      a[u]  = A[(size_t)(c0+u)*2048 + chain];
      bb[u] = B[(size_t)(c0+u)*2048 + chain];
    }
    #pragma unroll
    for(int u=0;u<8;u++){
      H[(size_t)(c0+u)*2048 + chain] = h;
      h = a[u]*h + bb[u];
    }
  }
}

// ---- fused scan pass3 + gnorm + act_quant ----
__global__ __launch_bounds__(256)
void scan3_gnorm(const unsigned short* __restrict__ ir, const unsigned short* __restrict__ fr,
                 const float* __restrict__ H, const unsigned short* __restrict__ g,
                 const float* __restrict__ gnw,
                 signed char* __restrict__ xq, float* __restrict__ rsx){
  __shared__ float s1[4], s2[4];
  int c = blockIdx.x, b = blockIdx.y;
  const int tid = threadIdx.x;
  int d0 = tid*4;
  size_t base = ((size_t)b*SJ + (size_t)c*TCH)*DM + d0;
  float4 hv = *(const float4*)(H + (size_t)c*2048 + b*1024 + d0);
  float h0=hv.x, h1=hv.y, h2=hv.z, h3=hv.w;
  float4 wv = ((const float4*)gnw)[tid];
  #pragma unroll
  for(int t=0;t<TCH;t++){
    ushort4 iv = *(const ushort4*)(ir + base + (size_t)t*DM);
    ushort4 fv = *(const ushort4*)(fr + base + (size_t)t*DM);
    float f0=sigm(bf2f(fv.x)), f1=sigm(bf2f(fv.y)), f2=sigm(bf2f(fv.z)), f3=sigm(bf2f(fv.w));
    float x0=bf2f(iv.x), x1=bf2f(iv.y), x2=bf2f(iv.z), x3=bf2f(iv.w);
    float p0=x0*sigm(x0)*(1.f-f0), p1=x1*sigm(x1)*(1.f-f1);
    float p2=x2*sigm(x2)*(1.f-f2), p3=x3*sigm(x3)*(1.f-f3);
    h0=f0*h0+p0; h1=f1*h1+p1; h2=f2*h2+p2; h3=f3*h3+p3;
    float ss = h0*h0+h1*h1+h2*h2+h3*h3, dummy = 0.f;
    blockSumSum(ss, dummy, s1, s2);
    float rms = rsqrtf(ss*(1.f/DM) + 1e-6f);
    ushort4 gv = *(const ushort4*)(g + base + (size_t)t*DM);
    float g0=bf2f(gv.x), g1=bf2f(gv.y), g2=bf2f(gv.z), g3=bf2f(gv.w);
    float n0 = h0*rms*wv.x*(g0*sigm(g0));
    float n1 = h1*rms*wv.y*(g1*sigm(g1));
    float n2 = h2*rms*wv.z*(g2*sigm(g2));
    float n3 = h3*rms*wv.w*(g3*sigm(g3));
    float ss2 = n0*n0+n1*n1+n2*n2+n3*n3;
    float mx  = fmaxf(fmaxf(fabsf(n0),fabsf(n1)),fmaxf(fabsf(n2),fabsf(n3)));
    blockSumMax(ss2, mx, s1, s2);
    float rms2  = rsqrtf(ss2*(1.f/DM) + 1e-6f);
    float amaxn = fmaxf(mx*rms2, 1e-5f);
    float k     = rms2*127.f/amaxn;
    char4 q;
    q.x = q8(n0*k,-128.f,127.f);
    q.y = q8(n1*k,-128.f,127.f);
    q.z = q8(n2*k,-128.f,127.f);
    q.w = q8(n3*k,-128.f,127.f);
    size_t row = (size_t)b*SJ + (size_t)c*TCH + t;
    *(char4*)(xq + row*DM + d0) = q;
    if(!tid) rsx[row] = amaxn*(1.f/127.f);
  }
}

// ---------------- epilogue ids ----------------
#define EPI_IFG    0
#define EPI_OUT    1
#define EPI_GLU    2

struct GemmP {
  const float* rsx;
  const float* swinv;
  unsigned short* outb;
  float* outf;
  const float* egate;
  int bshift;
  const signed char* w2;
};

template<int N>
__device__ __forceinline__ void vm_wait(){
  if constexpr(N==0)       asm volatile("s_waitcnt vmcnt(0)"  ::: "memory");
  else if constexpr(N==4)  asm volatile("s_waitcnt vmcnt(4)"  ::: "memory");
  else if constexpr(N==6)  asm volatile("s_waitcnt vmcnt(6)"  ::: "memory");
  else if constexpr(N==8)  asm volatile("s_waitcnt vmcnt(8)"  ::: "memory");
  else                     asm volatile("s_waitcnt vmcnt(12)" ::: "memory");
}

// ========== 2-barrier int8 GEMM, BK=64, 32x32x32 MFMA, triple-buffered ==========
// 256 threads (4 waves, 1xM 4xN). Per-wave output: 128 x {64,32,32} as 32x32 frags.
// LDS rows are 128B = two real 64B K-rows packed, XOR-swizzled on 16B units per row&7.
// A/B operand: lane holds 16 i8 at row = lane&31, k-16B-group = (lane>>5) within K=32.
// C/D: col = lane&31, row = (reg&3) + 8*(reg>>2) + 4*(lane>>5).
// VAR 0: BN=256 single-B | VAR 1: BN=128 dual-B (GLU) | VAR 2: BN=128 single-B
template<int VAR, int EPI, int SWZ>
__global__ __launch_bounds__(256, (VAR==2)?3:2)
void gemm8(const signed char* __restrict__ Aq, const signed char* __restrict__ Bq,
           int Ncols, int K, int lda, GemmP p){
  constexpr int BN   = (VAR==0)? 256 : 128;
  constexpr int NF   = (VAR==0)? 2 : 1;      // n-frags of 32 per matrix
  constexpr int NB2  = (VAR==1)? 2 : NF;     // B frag sets (dual for GLU)
  constexpr int BH   = (VAR==0)? 128 : 64;   // B half-stride (real rows)
  constexpr int TB   = (VAR==2)? 16384 : 24576;
  constexpr int NC   = (VAR==2)? 4 : 6;      // loads per tile per wave
  __shared__ char lds[3*TB];

  const int tid = threadIdx.x, wn = tid>>6, lane = tid&63;
  const int nwg = gridDim.x*gridDim.y;
  const int id  = blockIdx.y*gridDim.x + blockIdx.x;
  int nb, mb;
  if constexpr (SWZ==1){
    const int x = id&7, j = id>>3;
    nb = x*4 + (j&3);
    mb = j>>2;
  } else {
    const int wg = (id&7)*(nwg>>3) + (id>>3);
    nb = wg % gridDim.x; mb = wg / gridDim.x;
  }

  // ---- staging precompute (inverse-swizzled global source, linear LDS dest) ----
  const int sl = tid>>3;
  const int sd = (tid&7) ^ (sl&7);
  const int sdk = (sd&3)*16;
  const int sdh = sd>>2;
  const signed char* agp  = Aq + (size_t)(mb*128 + sl + sdh*64)*lda + sdk;
  const signed char* bg1p = Bq + (size_t)(nb*BN  + sl + sdh*BH)*lda + sdk;
  const signed char* bg2p = nullptr;
  if constexpr (VAR==1) bg2p = p.w2 + (size_t)(nb*128 + sl + sdh*64)*lda + sdk;

  auto stage = [&](char* buf, int k0){
    gl_lds16(agp + k0,           buf + tid*16);
    gl_lds16(agp + 32*lda + k0,  buf + 4096 + tid*16);
    if constexpr (VAR==0){
      gl_lds16(bg1p + k0,           buf + 8192  + tid*16);
      gl_lds16(bg1p + 32*lda + k0,  buf + 12288 + tid*16);
      gl_lds16(bg1p + 64*lda + k0,  buf + 16384 + tid*16);
      gl_lds16(bg1p + 96*lda + k0,  buf + 20480 + tid*16);
    } else if constexpr (VAR==1){
      gl_lds16(bg1p + k0,           buf + 8192  + tid*16);
      gl_lds16(bg1p + 32*lda + k0,  buf + 12288 + tid*16);
      gl_lds16(bg2p + k0,           buf + 16384 + tid*16);
      gl_lds16(bg2p + 32*lda + k0,  buf + 20480 + tid*16);
    } else {
      gl_lds16(bg1p + k0,           buf + 8192  + tid*16);
      gl_lds16(bg1p + 32*lda + k0,  buf + 12288 + tid*16);
    }
  };

  // ---- fragment read offsets: [frag][ks], k-16B-group g = ks*2 + (lane>>5) ----
  const int l31 = lane&31, lh = lane>>5;
  int aoff[4][2];
  #pragma unroll
  for(int mf=0;mf<4;mf++){
    int R = mf*32 + l31;
    #pragma unroll
    for(int ks=0;ks<2;ks++)
      aoff[mf][ks] = (R&63)*128 + ((((R>>6)<<2)|(ks*2+lh)) ^ (R&7))*16;
  }
  int boff[(VAR==0)?2:NB2][2];
  if constexpr (VAR==0){
    #pragma unroll
    for(int nf=0;nf<2;nf++){
      int RB = wn*64 + nf*32 + l31;
      #pragma unroll
      for(int ks=0;ks<2;ks++)
        boff[nf][ks] = 8192 + (RB&127)*128 + ((((RB>>7)<<2)|(ks*2+lh)) ^ (RB&7))*16;
    }
  } else {
    int RB = wn*32 + l31;
    #pragma unroll
    for(int m=0;m<NB2;m++)
      #pragma unroll
      for(int ks=0;ks<2;ks++)
        boff[m][ks] = 8192 + m*8192 + (RB&63)*128 + ((((RB>>6)<<2)|(ks*2+lh)) ^ (RB&7))*16;
  }

  i32x16 acc[4][NF];
  i32x16 acc2[(VAR==1)?4:1][NF];
  #pragma unroll
  for(int i=0;i<4;i++)
    #pragma unroll
    for(int j=0;j<NF;j++){
      acc[i][j]=(i32x16){0,0,0,0,0,0,0,0,0,0,0,0,0,0,0,0};
      if constexpr(VAR==1) acc2[i][j]=(i32x16){0,0,0,0,0,0,0,0,0,0,0,0,0,0,0,0};
    }

  auto tileBody = [&](const char* buf){
    i32x4 af[4][2];
    i32x4 bf_[(VAR==0)?2:NB2][2];
    #pragma unroll
    for(int mf=0;mf<4;mf++)
      #pragma unroll
      for(int ks=0;ks<2;ks++)
        af[mf][ks] = *(const i32x4*)(buf + aoff[mf][ks]);
    #pragma unroll
    for(int q=0;q<((VAR==0)?2:NB2);q++)
      #pragma unroll
      for(int ks=0;ks<2;ks++)
        bf_[q][ks] = *(const i32x4*)(buf + boff[q][ks]);
    #pragma unroll
    for(int ks=0;ks<2;ks++){
      #pragma unroll
      for(int mf=0;mf<4;mf++){
        #pragma unroll
        for(int nf=0;nf<NF;nf++){
          acc[mf][nf] = __builtin_amdgcn_mfma_i32_32x32x32_i8(af[mf][ks], bf_[nf][ks], acc[mf][nf], 0,0,0);
          if constexpr (VAR==1)
            acc2[mf][nf] = __builtin_amdgcn_mfma_i32_32x32x32_i8(af[mf][ks], bf_[1][ks], acc2[mf][nf], 0,0,0);
        }
      }
    }
  };

  // ---- main loop: triple buffer, prefetch depth 2 ----
  char* bufA = lds;
  char* bufB = lds + TB;
  char* bufC = lds + 2*TB;
  stage(bufA, 0);
  stage(bufB, 64);
  const int NT = K>>6;
  for(int t=0; t<NT-2; ++t){
    stage(bufC, (t+2)<<6);
    vm_wait<2*NC>();
    __builtin_amdgcn_s_barrier();
    __builtin_amdgcn_sched_barrier(0);
    tileBody(bufA);
    __builtin_amdgcn_sched_barrier(0);
    __builtin_amdgcn_s_barrier();
    char* tmp = bufA; bufA = bufB; bufB = bufC; bufC = tmp;
  }
  vm_wait<NC>();
  __builtin_amdgcn_s_barrier();
  __builtin_amdgcn_sched_barrier(0);
  tileBody(bufA);
  __builtin_amdgcn_sched_barrier(0);
  __builtin_amdgcn_s_barrier();
  vm_wait<0>();
  __builtin_amdgcn_s_barrier();
  __builtin_amdgcn_sched_barrier(0);
  tileBody(bufB);

  // ---- C write (32x32 layout: col=lane&31, row=(reg&3)+8*(reg>>2)+4*lh) ----
  float sw;
  if constexpr (EPI==EPI_IFG) sw = p.swinv[(nb*BN)>>10];
  else                        sw = *p.swinv;
  const int r0 = mb*128;
  const int c0 = nb*BN + wn*((VAR==0)?64:32);
  #pragma unroll
  for(int mf=0;mf<4;mf++){
    #pragma unroll
    for(int reg=0;reg<16;reg++){
      int r = r0 + mf*32 + (reg&3) + 8*(reg>>2) + 4*lh;
      float rs = p.rsx[r]*sw;
      #pragma unroll
      for(int nf=0;nf<NF;nf++){
        int c = c0 + nf*32 + l31;
        float val = (float)acc[mf][nf][reg]*rs;
        if constexpr (EPI==EPI_IFG){
          int mat = c >> 10;
          p.outb[(size_t)mat*9437184 + (size_t)r*1024 + (c&1023)] = f2bf(val);
        } else if constexpr (EPI==EPI_GLU){
          float v2 = (float)acc2[mf][nf][reg]*rs;
          p.outb[(size_t)r*Ncols + c] = f2bf(val*sigm(val)*v2);
        } else { // EPI_OUT
          p.outb[(size_t)r*Ncols + c] = f2bf(val);
        }
      }
    }
  }
}

// ---------------- small split-K int8 GEMM (ctx down-proj), atomic f32 ----------------
__global__ __launch_bounds__(256, 2)
void gemm_ra8(const signed char* __restrict__ Aq, const signed char* __restrict__ Wq,
              int K, int lda, GemmP p){
  __shared__ signed char As[128*128];
  __shared__ signed char Bs[128*128];
  const int tid = threadIdx.x;
  const int wave = tid>>6, lane = tid&63;
  const int nwg = gridDim.x*gridDim.y;
  const int id  = blockIdx.y*gridDim.x + blockIdx.x;
  const int wg  = (id&7)*(nwg>>3) + (id>>3);
  const int nb  = wg % gridDim.x, mb = wg / gridDim.x;
  const int wr = wave>>1, wc = wave&1;
  const int koff = blockIdx.z*K;

  const int grow = wave*8 + (lane>>3);
  const int gcol = (lane&7)*16;
  const signed char* ag = Aq + (size_t)(mb*128 + grow)*lda + koff + gcol;
  const signed char* bg = Wq + (size_t)(nb*128 + grow)*lda + koff + gcol;
  char* asl = (char*)As + wave*1024;
  char* bsl = (char*)Bs + wave*1024;

  i32x4 acc[4][4];
  #pragma unroll
  for(int i=0;i<4;i++)
    #pragma unroll
    for(int j=0;j<4;j++) acc[i][j] = (i32x4){0,0,0,0};

  const int lrow = lane&15, kq = lane>>4;
  const signed char* arow = &As[(wr*64 + lrow)*128 + kq*16];
  const signed char* brow = &Bs[(wc*64 + lrow)*128 + kq*16];

  for(int k0=0; k0<K; k0+=128){
    #pragma unroll
    for(int pp=0;pp<4;pp++){
      gl_lds16(ag + (size_t)pp*32*lda + k0, asl + pp*4096);
      gl_lds16(bg + (size_t)pp*32*lda + k0, bsl + pp*4096);
    }
    __syncthreads();
    #pragma unroll
    for(int kk=0;kk<2;kk++){
      i32x4 af[4], bfr[4];
      #pragma unroll
      for(int m=0;m<4;m++) af[m]  = *(const i32x4*)(arow + m*2048 + kk*64);
      #pragma unroll
      for(int n=0;n<4;n++) bfr[n] = *(const i32x4*)(brow + n*2048 + kk*64);
      #pragma unroll
      for(int m=0;m<4;m++)
        #pragma unroll
        for(int n=0;n<4;n++)
          acc[m][n] = __builtin_amdgcn_mfma_i32_16x16x64_i8(af[m], bfr[n], acc[m][n], 0,0,0);
    }
    __syncthreads();
  }

  const float sw = *p.swinv;
  const int r0 = mb*128 + wr*64, c0 = nb*128 + wc*64;
  #pragma unroll
  for(int m=0;m<4;m++){
    #pragma unroll
    for(int j=0;j<4;j++){
      int r = r0 + m*16 + kq*4 + j;
      float rs = p.rsx[r]*sw;
      #pragma unroll
      for(int n=0;n<4;n++){
        int c = c0 + n*16 + lrow;
        float val = (float)acc[m][n][j]*rs;
        int b = r >> p.bshift;
        size_t idx = (size_t)r*DM + c;
        atomicAdd(&p.outf[idx], p.egate[b*6144 + 5*1024 + c]*val);
      }
    }
  }
}

// ================= host =================
extern "C" void kernel_launch(void* const* d_in, const int* in_sizes, int n_in,
                              void* d_out, int out_size, void* d_ws, size_t ws_size,
                              hipStream_t stream){
  (void)in_sizes; (void)n_in; (void)out_size; (void)ws_size;
  const float* hidden   = (const float*)d_in[0];
  const float* enc      = (const float*)d_in[1];
  const float* temb     = (const float*)d_in[2];
  const float* adaln_w  = (const float*)d_in[3];
  const float* adaln_b  = (const float*)d_in[4];
  const float* adaln_cw = (const float*)d_in[5];
  const float* adaln_cb = (const float*)d_in[6];
  const float* wi  = (const float*)d_in[7];
  const float* wf  = (const float*)d_in[8];
  const float* wg  = (const float*)d_in[9];
  const float* wo  = (const float*)d_in[10];
  const float* gnw = (const float*)d_in[11];
  const float* ffg = (const float*)d_in[12];
  const float* ffd = (const float*)d_in[13];
  const float* fcg = (const float*)d_in[14];
  const float* fcd = (const float*)d_in[15];

  const size_t MB = 1024ull*1024ull;
  char* ws = (char*)d_ws;
  signed char* W8_IFG = (signed char*)(ws + 0*MB);
  signed char* W8_WO  = (signed char*)(ws + 3*MB);
  signed char* W8_FFG = (signed char*)(ws + 4*MB);
  signed char* W8_FFD = (signed char*)(ws + 12*MB);
  signed char* W8_FCG = (signed char*)(ws + 16*MB);
  signed char* W8_FCD = (signed char*)(ws + 24*MB);
  float* PART  = (float*)(ws + 28*MB);
  float* SWINV = (float*)(ws + 28*MB + 32*1024);
  float* EH    = (float*)(ws + 28*MB + 64*1024);
  float* EC    = (float*)(ws + 28*MB + 112*1024);
  float* RSX1  = (float*)(ws + 28*MB + 160*1024);
  float* RSX2  = (float*)(ws + 28*MB + 200*1024);
  float* RSX3  = (float*)(ws + 28*MB + 240*1024);
  float* RSXZ  = (float*)(ws + 28*MB + 280*1024);
  float* RSX4  = (float*)(ws + 28*MB + 320*1024);
  float* RSXZC = (float*)(ws + 28*MB + 328*1024);
  float* SCANA = (float*)(ws + 29*MB);
  float* SCANB = (float*)(ws + 33*MB);
  float* SCANH = (float*)(ws + 37*MB);
  signed char* XQ8 = (signed char*)(ws + 41*MB);
  unsigned short* IRAW = (unsigned short*)(ws + 51*MB);
  unsigned short* FRAW = (unsigned short*)(ws + 69*MB);
  unsigned short* GRAW = (unsigned short*)(ws + 87*MB);
  unsigned short* ATTN = (unsigned short*)(ws + 51*MB);
  signed char* SG8 = (signed char*)(ws + 51*MB);
  unsigned short* MLPH = (unsigned short*)(ws + 83*MB);
  float* HNEW = (float*)(ws + 105*MB);
  unsigned short* SGB = (unsigned short*)(ws + 137*MB);
  float* OUT_H = (float*)d_out;
  float* OUT_C = (float*)d_out + 8388608;

  // ---- weight quantization ----
  WList L;
  L.w[0]=wi;  L.n[0]=1048576ull; L.q[0]=W8_IFG;
  L.w[1]=wf;  L.n[1]=1048576ull; L.q[1]=W8_IFG + 1048576;
  L.w[2]=wg;  L.n[2]=1048576ull; L.q[2]=W8_IFG + 2097152;
  L.w[3]=wo;  L.n[3]=1048576ull; L.q[3]=W8_WO;
  L.w[4]=ffg; L.n[4]=8388608ull; L.q[4]=W8_FFG;
  L.w[5]=ffd; L.n[5]=4194304ull; L.q[5]=W8_FFD;
  L.w[6]=fcg; L.n[6]=8388608ull; L.q[6]=W8_FCG;
  L.w[7]=fcd; L.n[7]=4194304ull; L.q[7]=W8_FCD;
  wq_reduce  <<<dim3(512,8), 256, 0, stream>>>(L, PART);
  wq_finalize<<<8,          256, 0, stream>>>(L, PART, SWINV);
  wq_quant   <<<dim3(1024,8),256, 0, stream>>>(L, SWINV);

  // ---- adaLN embeddings ----
  adaln_gemv<<<dim3(1536,2), 256, 0, stream>>>(temb, adaln_w,  adaln_b,  EH);
  adaln_gemv<<<dim3(1536,2), 256, 0, stream>>>(temb, adaln_cw, adaln_cb, EC);

  // ---- joint = [adaLN(enc); adaLN(hidden)], rmsnorm+quant (int8) ----
  modnorm_quant<<<1024, 256, 0, stream>>>(enc,    9,  EC, 0, 1024, XQ8, RSX1, 0,   SJ);
  modnorm_quant<<<8192, 256, 0, stream>>>(hidden, 12, EH, 0, 1024, XQ8, RSX1, 512, SJ);

  // ---- merged i/f/g bitlinear (N=3072) ----
  GemmP p{};
  p.rsx = RSX1; p.swinv = SWINV; p.outb = IRAW;
  gemm8<0,EPI_IFG,0><<<dim3(12,72), 256, 0, stream>>>(XQ8, W8_IFG, 3072, 1024, 1024, p);

  // ---- HGRN scan + fused gnorm/quant ----
  scan_pass1<<<dim3(NCH,2), 256, 0, stream>>>(IRAW, FRAW, SCANA, SCANB);
  scan_pass2<<<8,           256, 0, stream>>>(SCANA, SCANB, SCANH);
  scan3_gnorm<<<dim3(NCH,2), 256, 0, stream>>>(IRAW, FRAW, SCANH, GRAW, gnw, XQ8, RSX2);

  // ---- wo bitlinear -> bf16 ATTN ----
  GemmP pw{};
  pw.rsx = RSX2; pw.swinv = SWINV+3; pw.outb = ATTN;
  gemm8<2,EPI_OUT,0><<<dim3(8,72), 256, 0, stream>>>(XQ8, W8_WO, 1024, 1024, 1024, pw);

  // ---- fused residual + LN/mod/rmsnorm/quant ----
  resid_modnorm<<<8192, 256, 0, stream>>>(hidden, ATTN, 512, 12, EH, HNEW, XQ8, RSX3);
  resid_modnorm<<<1024, 256, 0, stream>>>(enc,    ATTN, 0,   9,  EC, OUT_C,
                                          XQ8 + (size_t)8192*1024, RSX4);

  // ---- image MLP ----
  GemmP pg{};
  pg.rsx = RSX3; pg.swinv = SWINV+4; pg.outb = SGB; pg.w2 = W8_FFG + (size_t)4096*1024;
  gemm8<1,EPI_GLU,1><<<dim3(32,64), 256, 0, stream>>>(XQ8, W8_FFG, 4096, 1024, 1024, pg);
  rmsq4096<<<8192, 256, 0, stream>>>(SGB, SG8, RSXZ);
  GemmP pd{};
  pd.rsx = RSXZ; pd.swinv = SWINV+5; pd.outb = MLPH;
  gemm8<2,EPI_OUT,0><<<dim3(8,64), 256, 0, stream>>>(SG8, W8_FFD, 1024, 4096, 4096, pd);
  resid_out<<<8192, 256, 0, stream>>>(HNEW, MLPH, EH, 12, OUT_H);

  // ---- context MLP ----
  GemmP pc{};
  pc.rsx = RSX4; pc.swinv = SWINV+6; pc.outb = SGB; pc.w2 = W8_FCG + (size_t)4096*1024;
  gemm8<1,EPI_GLU,1><<<dim3(32,8), 256, 0, stream>>>(XQ8 + (size_t)8192*1024, W8_FCG, 4096, 1024, 1024, pc);
  rmsq4096<<<1024, 256, 0, stream>>>(SGB, SG8, RSXZC);
  GemmP pe{};
  pe.rsx = RSXZC; pe.swinv = SWINV+7; pe.outf = OUT_C; pe.egate = EC; pe.bshift = 9;
  gemm_ra8<<<dim3(8,8,4), 256, 0, stream>>>(SG8, W8_FCD, 1024, 4096, pe);
}

// Round 13
// 468.209 us; speedup vs baseline: 1.0475x; 1.0475x over previous
//
#include <hip/hip_runtime.h>
#include <hip/hip_bf16.h>
#include <stdint.h>

#define DM   1024
#define SJ   4608
#define SCTX 512
#define SIMG 4096
#define NCH  512
#define TCH  9

typedef __attribute__((ext_vector_type(4))) int   i32x4;
typedef __attribute__((ext_vector_type(4))) float f32x4;

__device__ __forceinline__ float bf2f(unsigned short u){
  union { unsigned int i; float f; } v; v.i = ((unsigned int)u) << 16; return v.f;
}
__device__ __forceinline__ unsigned short f2bf(float f){
  unsigned int u = __float_as_uint(f);
  u += 0x7fffu + ((u >> 16) & 1u);
  return (unsigned short)(u >> 16);
}
__device__ __forceinline__ float sigm(float x){ return 1.f/(1.f+__expf(-x)); }
__device__ __forceinline__ signed char q8(float v, float lo, float hi){
  return (signed char)(int)fminf(fmaxf(rintf(v),lo),hi);
}

__device__ __forceinline__ float wsum(float v){
  #pragma unroll
  for(int o=32;o>0;o>>=1) v += __shfl_xor(v,o);
  return v;
}
__device__ __forceinline__ float wmax(float v){
  #pragma unroll
  for(int o=32;o>0;o>>=1) v = fmaxf(v,__shfl_xor(v,o));
  return v;
}
__device__ __forceinline__ void blockSumSum(float& a, float& b, float* s1, float* s2){
  a = wsum(a); b = wsum(b);
  if(!(threadIdx.x&63)){ s1[threadIdx.x>>6]=a; s2[threadIdx.x>>6]=b; }
  __syncthreads();
  a = s1[0]+s1[1]+s1[2]+s1[3];
  b = s2[0]+s2[1]+s2[2]+s2[3];
  __syncthreads();
}
__device__ __forceinline__ void blockSumMax(float& a, float& b, float* s1, float* s2){
  a = wsum(a); b = wmax(b);
  if(!(threadIdx.x&63)){ s1[threadIdx.x>>6]=a; s2[threadIdx.x>>6]=b; }
  __syncthreads();
  a = s1[0]+s1[1]+s1[2]+s1[3];
  b = fmaxf(fmaxf(s2[0],s2[1]),fmaxf(s2[2],s2[3]));
  __syncthreads();
}

// ---------------- async global->LDS ----------------
typedef __attribute__((address_space(1))) void gvoid_t;
typedef __attribute__((address_space(3))) void lvoid_t;
__device__ __forceinline__ void gl_lds16(const void* g, void* l){
  __builtin_amdgcn_global_load_lds((gvoid_t*)g, (lvoid_t*)l, 16, 0, 0);
}

// ---------------- weight quantization ----------------
struct WList {
  const float* w[8];
  unsigned long long n[8];
  signed char* q[8];
};

__global__ __launch_bounds__(256)
void wq_reduce(WList L, float* __restrict__ part){
  __shared__ float s1[4];
  int m = blockIdx.y;
  const float4* w4 = (const float4*)L.w[m];
  size_t n4 = L.n[m] >> 2;
  float s = 0.f;
  for(size_t i = (size_t)blockIdx.x*256 + threadIdx.x; i < n4; i += (size_t)512*256){
    float4 v = w4[i];
    s += fabsf(v.x)+fabsf(v.y)+fabsf(v.z)+fabsf(v.w);
  }
  s = wsum(s);
  if(!(threadIdx.x&63)) s1[threadIdx.x>>6] = s;
  __syncthreads();
  if(!threadIdx.x) part[m*512 + blockIdx.x] = s1[0]+s1[1]+s1[2]+s1[3];
}

__global__ __launch_bounds__(256)
void wq_finalize(WList L, const float* __restrict__ part, float* __restrict__ swinv){
  __shared__ float s1[4];
  int m = blockIdx.x;
  float s = part[m*512 + threadIdx.x] + part[m*512 + 256 + threadIdx.x];
  s = wsum(s);
  if(!(threadIdx.x&63)) s1[threadIdx.x>>6] = s;
  __syncthreads();
  if(!threadIdx.x){
    float mean = (s1[0]+s1[1]+s1[2]+s1[3]) / (float)L.n[m];
    swinv[m] = fmaxf(mean, 1e-5f);
  }
}

__global__ __launch_bounds__(256)
void wq_quant(WList L, const float* __restrict__ swinv){
  int m = blockIdx.y;
  float sc = 1.f / swinv[m];
  const float4* w4 = (const float4*)L.w[m];
  signed char* q = L.q[m];
  size_t n4 = L.n[m] >> 2;
  for(size_t i = (size_t)blockIdx.x*256 + threadIdx.x; i < n4; i += (size_t)1024*256){
    float4 v = w4[i];
    char4 o;
    o.x = q8(v.x*sc,-1.f,1.f);
    o.y = q8(v.y*sc,-1.f,1.f);
    o.z = q8(v.z*sc,-1.f,1.f);
    o.w = q8(v.w*sc,-1.f,1.f);
    ((char4*)q)[i] = o;
  }
}

// ---------------- adaLN embedding GEMV (both tables in one launch) ----------------
__global__ __launch_bounds__(256)
void adaln_gemv2(const float* __restrict__ temb,
                 const float* __restrict__ W1, const float* __restrict__ B1, float* __restrict__ E1,
                 const float* __restrict__ W2, const float* __restrict__ B2, float* __restrict__ E2){
  const float* W  = blockIdx.z ? W2 : W1;
  const float* bs = blockIdx.z ? B2 : B1;
  float* e        = blockIdx.z ? E2 : E1;
  int o = blockIdx.x*4 + (threadIdx.x>>6);
  int b = blockIdx.y;
  int lane = threadIdx.x & 63;
  const float4* t4 = (const float4*)(temb + b*DM);
  const float4* w4 = (const float4*)(W + (size_t)o*DM);
  float acc = 0.f;
  #pragma unroll
  for(int i=0;i<4;i++){
    float4 tv = t4[i*64+lane], wv = w4[i*64+lane];
    acc += (tv.x*sigm(tv.x))*wv.x + (tv.y*sigm(tv.y))*wv.y
         + (tv.z*sigm(tv.z))*wv.z + (tv.w*sigm(tv.w))*wv.w;
  }
  acc = wsum(acc);
  if(!lane) e[b*6144 + o] = acc + bs[o];
}

// ---------------- joint LN -> modulate -> rmsnorm -> act_quant (enc+hidden, one launch) ----
__global__ __launch_bounds__(256)
void modnorm_joint(const float* __restrict__ enc, const float* __restrict__ hidden,
                   const float* __restrict__ EC, const float* __restrict__ EH,
                   signed char* __restrict__ xq, float* __restrict__ rsx){
  __shared__ float s1[4], s2[4];
  const int tid = threadIdx.x;
  const int row = blockIdx.x;
  const float* x; const float* e; int orow;
  if (row < 1024){
    int b = row >> 9, s = row & 511;
    x = enc + (size_t)row*DM; e = EC + b*6144; orow = b*SJ + s;
  } else {
    int r2 = row - 1024;
    int b = r2 >> 12, s = r2 & 4095;
    x = hidden + (size_t)r2*DM; e = EH + b*6144; orow = b*SJ + 512 + s;
  }
  float4 xv = ((const float4*)x)[tid];
  float sum = xv.x+xv.y+xv.z+xv.w;
  float ss  = xv.x*xv.x+xv.y*xv.y+xv.z*xv.z+xv.w*xv.w;
  blockSumSum(sum, ss, s1, s2);
  float mu  = sum * (1.f/DM);
  float inv = rsqrtf(ss*(1.f/DM) - mu*mu + 1e-6f);
  float4 scv = ((const float4*)(e + 0))[tid];
  float4 shv = ((const float4*)(e + 1024))[tid];
  float n0 = (xv.x-mu)*inv*(1.f+scv.x)+shv.x;
  float n1 = (xv.y-mu)*inv*(1.f+scv.y)+shv.y;
  float n2 = (xv.z-mu)*inv*(1.f+scv.z)+shv.z;
  float n3 = (xv.w-mu)*inv*(1.f+scv.w)+shv.w;
  float ss2 = n0*n0+n1*n1+n2*n2+n3*n3;
  float mx  = fmaxf(fmaxf(fabsf(n0),fabsf(n1)),fmaxf(fabsf(n2),fabsf(n3)));
  blockSumMax(ss2, mx, s1, s2);
  float rms   = rsqrtf(ss2*(1.f/DM) + 1e-6f);
  float amaxn = fmaxf(mx*rms, 1e-5f);
  float k     = rms*127.f/amaxn;
  char4 q;
  q.x = q8(n0*k,-128.f,127.f);
  q.y = q8(n1*k,-128.f,127.f);
  q.z = q8(n2*k,-128.f,127.f);
  q.w = q8(n3*k,-128.f,127.f);
  ((char4*)(xq + (size_t)orow*DM))[tid] = q;
  if(!tid) rsx[orow] = amaxn*(1.f/127.f);
}

// ---- joint residual+gate+LN/mod/rmsnorm/quant for ctx (rows<1024) and img ----
__global__ __launch_bounds__(256)
void resid_modnorm_joint(const float* __restrict__ hidden, const float* __restrict__ enc,
                         const unsigned short* __restrict__ attn,
                         const float* __restrict__ EH, const float* __restrict__ EC,
                         float* __restrict__ HNEW, float* __restrict__ OUTC,
                         signed char* __restrict__ xqi, signed char* __restrict__ xqc,
                         float* __restrict__ rsxi, float* __restrict__ rsxc){
  __shared__ float s1[4], s2[4];
  const int tid = threadIdx.x;
  const int row = blockIdx.x;
  const float* x; const float* e; float* hout; signed char* xq; float* rsx;
  int arow, lrow;
  if (row < 1024){
    int b = row >> 9, s = row & 511;
    x = enc + (size_t)row*DM; e = EC + b*6144; hout = OUTC + (size_t)row*DM;
    xq = xqc; rsx = rsxc; lrow = row; arow = b*SJ + s;
  } else {
    int r2 = row - 1024;
    int b = r2 >> 12, s = r2 & 4095;
    x = hidden + (size_t)r2*DM; e = EH + b*6144; hout = HNEW + (size_t)r2*DM;
    xq = xqi; rsx = rsxi; lrow = r2; arow = b*SJ + 512 + s;
  }
  float4 xv = ((const float4*)x)[tid];
  ushort4 av = ((const ushort4*)(attn + (size_t)arow*DM))[tid];
  float4 gv = ((const float4*)(e + 2*1024))[tid];
  float h0 = xv.x + gv.x*bf2f(av.x);
  float h1 = xv.y + gv.y*bf2f(av.y);
  float h2 = xv.z + gv.z*bf2f(av.z);
  float h3 = xv.w + gv.w*bf2f(av.w);
  ((float4*)hout)[tid] = make_float4(h0,h1,h2,h3);
  float sum = h0+h1+h2+h3;
  float ss  = h0*h0+h1*h1+h2*h2+h3*h3;
  blockSumSum(sum, ss, s1, s2);
  float mu  = sum * (1.f/DM);
  float inv = rsqrtf(ss*(1.f/DM) - mu*mu + 1e-6f);
  float4 scv = ((const float4*)(e + 3*1024))[tid];
  float4 shv = ((const float4*)(e + 4*1024))[tid];
  float n0 = (h0-mu)*inv*(1.f+scv.x)+shv.x;
  float n1 = (h1-mu)*inv*(1.f+scv.y)+shv.y;
  float n2 = (h2-mu)*inv*(1.f+scv.z)+shv.z;
  float n3 = (h3-mu)*inv*(1.f+scv.w)+shv.w;
  float ss2 = n0*n0+n1*n1+n2*n2+n3*n3;
  float mx  = fmaxf(fmaxf(fabsf(n0),fabsf(n1)),fmaxf(fabsf(n2),fabsf(n3)));
  blockSumMax(ss2, mx, s1, s2);
  float rms   = rsqrtf(ss2*(1.f/DM) + 1e-6f);
  float amaxn = fmaxf(mx*rms, 1e-5f);
  float k     = rms*127.f/amaxn;
  char4 q;
  q.x = q8(n0*k,-128.f,127.f);
  q.y = q8(n1*k,-128.f,127.f);
  q.z = q8(n2*k,-128.f,127.f);
  q.w = q8(n3*k,-128.f,127.f);
  ((char4*)(xq + (size_t)lrow*DM))[tid] = q;
  if(!tid) rsx[lrow] = amaxn*(1.f/127.f);
}

// ---------------- rmsnorm -> act_quant, bf16 D=4096 rows -> int8 ----------------
__global__ __launch_bounds__(256)
void rmsq4096(const unsigned short* __restrict__ z, signed char* __restrict__ zq,
              float* __restrict__ rsx){
  __shared__ float s1[4], s2[4];
  const int tid = threadIdx.x;
  const unsigned short* zr = z + (size_t)blockIdx.x*4096;
  signed char* qr = zq + (size_t)blockIdx.x*4096;
  float v[16];
  #pragma unroll
  for(int i=0;i<4;i++){
    ushort4 u = ((const ushort4*)zr)[tid + i*256];
    v[i*4+0]=bf2f(u.x); v[i*4+1]=bf2f(u.y); v[i*4+2]=bf2f(u.z); v[i*4+3]=bf2f(u.w);
  }
  float ss=0.f, mx=0.f;
  #pragma unroll
  for(int i=0;i<16;i++){ ss += v[i]*v[i]; mx = fmaxf(mx, fabsf(v[i])); }
  blockSumMax(ss, mx, s1, s2);
  float rms   = rsqrtf(ss*(1.f/4096.f) + 1e-6f);
  float amaxn = fmaxf(mx*rms, 1e-5f);
  float k     = rms*127.f/amaxn;
  #pragma unroll
  for(int i=0;i<4;i++){
    char4 q;
    q.x = q8(v[i*4+0]*k,-128.f,127.f);
    q.y = q8(v[i*4+1]*k,-128.f,127.f);
    q.z = q8(v[i*4+2]*k,-128.f,127.f);
    q.w = q8(v[i*4+3]*k,-128.f,127.f);
    ((char4*)qr)[tid + i*256] = q;
  }
  if(!tid) rsx[blockIdx.x] = amaxn*(1.f/127.f);
}

// ---------------- HGRN chunked scan ----------------
__global__ __launch_bounds__(256)
void scan_pass1(const unsigned short* __restrict__ ir, const unsigned short* __restrict__ fr,
                float* __restrict__ A, float* __restrict__ B){
  int c = blockIdx.x, b = blockIdx.y;
  int d0 = threadIdx.x*4;
  size_t base = ((size_t)b*SJ + (size_t)c*TCH)*DM + d0;
  float a0=1,a1=1,a2=1,a3=1, h0=0,h1=0,h2=0,h3=0;
  #pragma unroll
  for(int t=0;t<TCH;t++){
    ushort4 iv = *(const ushort4*)(ir + base + (size_t)t*DM);
    ushort4 fv = *(const ushort4*)(fr + base + (size_t)t*DM);
    float f0=sigm(bf2f(fv.x)), f1=sigm(bf2f(fv.y)), f2=sigm(bf2f(fv.z)), f3=sigm(bf2f(fv.w));
    float x0=bf2f(iv.x), x1=bf2f(iv.y), x2=bf2f(iv.z), x3=bf2f(iv.w);
    float p0=x0*sigm(x0)*(1.f-f0), p1=x1*sigm(x1)*(1.f-f1);
    float p2=x2*sigm(x2)*(1.f-f2), p3=x3*sigm(x3)*(1.f-f3);
    h0=f0*h0+p0; h1=f1*h1+p1; h2=f2*h2+p2; h3=f3*h3+p3;
    a0*=f0; a1*=f1; a2*=f2; a3*=f3;
  }
  size_t idx = (size_t)c*2048 + b*1024 + d0;
  *(float4*)(A + idx) = make_float4(a0,a1,a2,a3);
  *(float4*)(B + idx) = make_float4(h0,h1,h2,h3);
}

__global__ __launch_bounds__(256)
void scan_pass2(const float* __restrict__ A, const float* __restrict__ B, float* __restrict__ H){
  int chain = blockIdx.x*256 + threadIdx.x;
  float h = 0.f;
  for(int c0=0;c0<NCH;c0+=8){
    float a[8], bb[8];
    #pragma unroll
    for(int u=0;u<8;u++){
      a[u]  = A[(size_t)(c0+u)*2048 + chain];
      bb[u] = B[(size_t)(c0+u)*2048 + chain];
    }
    #pragma unroll
    for(int u=0;u<8;u++){
      H[(size_t)(c0+u)*2048 + chain] = h;
      h = a[u]*h + bb[u];
    }
  }
}

// ---- fused scan pass3 + gnorm + act_quant ----
__global__ __launch_bounds__(256)
void scan3_gnorm(const unsigned short* __restrict__ ir, const unsigned short* __restrict__ fr,
                 const float* __restrict__ H, const unsigned short* __restrict__ g,
                 const float* __restrict__ gnw,
                 signed char* __restrict__ xq, float* __restrict__ rsx){
  __shared__ float s1[4], s2[4];
  int c = blockIdx.x, b = blockIdx.y;
  const int tid = threadIdx.x;
  int d0 = tid*4;
  size_t base = ((size_t)b*SJ + (size_t)c*TCH)*DM + d0;
  float4 hv = *(const float4*)(H + (size_t)c*2048 + b*1024 + d0);
  float h0=hv.x, h1=hv.y, h2=hv.z, h3=hv.w;
  float4 wv = ((const float4*)gnw)[tid];
  #pragma unroll
  for(int t=0;t<TCH;t++){
    ushort4 iv = *(const ushort4*)(ir + base + (size_t)t*DM);
    ushort4 fv = *(const ushort4*)(fr + base + (size_t)t*DM);
    float f0=sigm(bf2f(fv.x)), f1=sigm(bf2f(fv.y)), f2=sigm(bf2f(fv.z)), f3=sigm(bf2f(fv.w));
    float x0=bf2f(iv.x), x1=bf2f(iv.y), x2=bf2f(iv.z), x3=bf2f(iv.w);
    float p0=x0*sigm(x0)*(1.f-f0), p1=x1*sigm(x1)*(1.f-f1);
    float p2=x2*sigm(x2)*(1.f-f2), p3=x3*sigm(x3)*(1.f-f3);
    h0=f0*h0+p0; h1=f1*h1+p1; h2=f2*h2+p2; h3=f3*h3+p3;
    float ss = h0*h0+h1*h1+h2*h2+h3*h3, dummy = 0.f;
    blockSumSum(ss, dummy, s1, s2);
    float rms = rsqrtf(ss*(1.f/DM) + 1e-6f);
    ushort4 gv = *(const ushort4*)(g + base + (size_t)t*DM);
    float g0=bf2f(gv.x), g1=bf2f(gv.y), g2=bf2f(gv.z), g3=bf2f(gv.w);
    float n0 = h0*rms*wv.x*(g0*sigm(g0));
    float n1 = h1*rms*wv.y*(g1*sigm(g1));
    float n2 = h2*rms*wv.z*(g2*sigm(g2));
    float n3 = h3*rms*wv.w*(g3*sigm(g3));
    float ss2 = n0*n0+n1*n1+n2*n2+n3*n3;
    float mx  = fmaxf(fmaxf(fabsf(n0),fabsf(n1)),fmaxf(fabsf(n2),fabsf(n3)));
    blockSumMax(ss2, mx, s1, s2);
    float rms2  = rsqrtf(ss2*(1.f/DM) + 1e-6f);
    float amaxn = fmaxf(mx*rms2, 1e-5f);
    float k     = rms2*127.f/amaxn;
    char4 q;
    q.x = q8(n0*k,-128.f,127.f);
    q.y = q8(n1*k,-128.f,127.f);
    q.z = q8(n2*k,-128.f,127.f);
    q.w = q8(n3*k,-128.f,127.f);
    size_t row = (size_t)b*SJ + (size_t)c*TCH + t;
    *(char4*)(xq + row*DM + d0) = q;
    if(!tid) rsx[row] = amaxn*(1.f/127.f);
  }
}

// ---------------- epilogue ids ----------------
#define EPI_IFG    0
#define EPI_OUT    1
#define EPI_GLU    2
#define EPI_RESID  3

struct GemmP {
  const float* rsx;
  const float* swinv;
  unsigned short* outb;
  float* outf;
  const float* resid;
  const float* egate;
  int bshift;
  const signed char* w2;
};

template<int N>
__device__ __forceinline__ void vm_wait(){
  if constexpr(N==0)       asm volatile("s_waitcnt vmcnt(0)"  ::: "memory");
  else if constexpr(N==4)  asm volatile("s_waitcnt vmcnt(4)"  ::: "memory");
  else if constexpr(N==6)  asm volatile("s_waitcnt vmcnt(6)"  ::: "memory");
  else if constexpr(N==8)  asm volatile("s_waitcnt vmcnt(8)"  ::: "memory");
  else                     asm volatile("s_waitcnt vmcnt(12)" ::: "memory");
}

// ========== 2-barrier int8 GEMM, BK=64, 16x16x64 MFMA, triple-buffered depth-2 ==========
template<int VAR, int EPI, int SWZ>
__global__ __launch_bounds__(256, (VAR==2)?3:2)
void gemm8(const signed char* __restrict__ Aq, const signed char* __restrict__ Bq,
           int Ncols, int K, int lda, GemmP p){
  constexpr int BN   = (VAR==0)? 256 : 128;
  constexpr int NF   = (VAR==0)? 4 : 2;
  constexpr int NBF  = (VAR==1)? 4 : NF;
  constexpr int BH   = (VAR==0)? 128 : 64;
  constexpr int TB   = (VAR==2)? 16384 : 24576;
  constexpr int NC   = (VAR==2)? 4 : 6;
  __shared__ char lds[3*TB];

  const int tid = threadIdx.x, wn = tid>>6, lane = tid&63;
  const int nwg = gridDim.x*gridDim.y;
  const int id  = blockIdx.y*gridDim.x + blockIdx.x;
  int nb, mb;
  if constexpr (SWZ==1){
    const int x = id&7, j = id>>3;
    nb = x*4 + (j&3);
    mb = j>>2;
  } else {
    const int wg = (id&7)*(nwg>>3) + (id>>3);
    nb = wg % gridDim.x; mb = wg / gridDim.x;
  }

  const int sl = tid>>3;
  const int sd = (tid&7) ^ (sl&7);
  const int sdk = (sd&3)*16;
  const int sdh = sd>>2;
  const signed char* agp  = Aq + (size_t)(mb*128 + sl + sdh*64)*lda + sdk;
  const signed char* bg1p = Bq + (size_t)(nb*BN  + sl + sdh*BH)*lda + sdk;
  const signed char* bg2p = nullptr;
  if constexpr (VAR==1) bg2p = p.w2 + (size_t)(nb*128 + sl + sdh*64)*lda + sdk;

  auto stage = [&](char* buf, int k0){
    gl_lds16(agp + k0,           buf + tid*16);
    gl_lds16(agp + 32*lda + k0,  buf + 4096 + tid*16);
    if constexpr (VAR==0){
      gl_lds16(bg1p + k0,           buf + 8192  + tid*16);
      gl_lds16(bg1p + 32*lda + k0,  buf + 12288 + tid*16);
      gl_lds16(bg1p + 64*lda + k0,  buf + 16384 + tid*16);
      gl_lds16(bg1p + 96*lda + k0,  buf + 20480 + tid*16);
    } else if constexpr (VAR==1){
      gl_lds16(bg1p + k0,           buf + 8192  + tid*16);
      gl_lds16(bg1p + 32*lda + k0,  buf + 12288 + tid*16);
      gl_lds16(bg2p + k0,           buf + 16384 + tid*16);
      gl_lds16(bg2p + 32*lda + k0,  buf + 20480 + tid*16);
    } else {
      gl_lds16(bg1p + k0,           buf + 8192  + tid*16);
      gl_lds16(bg1p + 32*lda + k0,  buf + 12288 + tid*16);
    }
  };

  const int lr = lane&15, kq = lane>>4;
  int aoff[8];
  #pragma unroll
  for(int mf=0;mf<8;mf++){
    int R = mf*16 + lr;
    aoff[mf] = (R&63)*128 + ((((R>>6)<<2)|kq) ^ (R&7))*16;
  }
  int boff[NBF];
  if constexpr (VAR==0){
    #pragma unroll
    for(int nf=0;nf<4;nf++){
      int RB = wn*64 + nf*16 + lr;
      boff[nf] = 8192 + (RB&127)*128 + ((((RB>>7)<<2)|kq) ^ (RB&7))*16;
    }
  } else {
    #pragma unroll
    for(int m=0;m<((VAR==1)?2:1);m++){
      #pragma unroll
      for(int nf=0;nf<2;nf++){
        int RB = wn*32 + nf*16 + lr;
        boff[m*2+nf] = 8192 + m*8192 + (RB&63)*128 + ((((RB>>6)<<2)|kq) ^ (RB&7))*16;
      }
    }
  }

  i32x4 acc[8][NF];
  i32x4 acc2[(VAR==1)?8:1][NF];
  #pragma unroll
  for(int i=0;i<8;i++)
    #pragma unroll
    for(int j=0;j<NF;j++){ acc[i][j]=(i32x4){0,0,0,0}; if constexpr(VAR==1) acc2[i][j]=(i32x4){0,0,0,0}; }

  auto tileBody = [&](const char* buf){
    i32x4 af[8], bf_[NBF];
    #pragma unroll
    for(int mf=0;mf<8;mf++) af[mf] = *(const i32x4*)(buf + aoff[mf]);
    #pragma unroll
    for(int q=0;q<NBF;q++)  bf_[q] = *(const i32x4*)(buf + boff[q]);
    #pragma unroll
    for(int mf=0;mf<8;mf++){
      #pragma unroll
      for(int nf=0;nf<NF;nf++){
        acc[mf][nf] = __builtin_amdgcn_mfma_i32_16x16x64_i8(af[mf], bf_[nf], acc[mf][nf], 0,0,0);
        if constexpr (VAR==1)
          acc2[mf][nf] = __builtin_amdgcn_mfma_i32_16x16x64_i8(af[mf], bf_[NF+nf], acc2[mf][nf], 0,0,0);
      }
    }
  };

  char* bufA = lds;
  char* bufB = lds + TB;
  char* bufC = lds + 2*TB;
  stage(bufA, 0);
  stage(bufB, 64);
  const int NT = K>>6;
  for(int t=0; t<NT-2; ++t){
    stage(bufC, (t+2)<<6);
    vm_wait<2*NC>();
    __builtin_amdgcn_s_barrier();
    __builtin_amdgcn_sched_barrier(0);
    tileBody(bufA);
    __builtin_amdgcn_sched_barrier(0);
    __builtin_amdgcn_s_barrier();
    char* tmp = bufA; bufA = bufB; bufB = bufC; bufC = tmp;
  }
  vm_wait<NC>();
  __builtin_amdgcn_s_barrier();
  __builtin_amdgcn_sched_barrier(0);
  tileBody(bufA);
  __builtin_amdgcn_sched_barrier(0);
  __builtin_amdgcn_s_barrier();
  vm_wait<0>();
  __builtin_amdgcn_s_barrier();
  __builtin_amdgcn_sched_barrier(0);
  tileBody(bufB);

  // ---- C write ----
  float sw;
  if constexpr (EPI==EPI_IFG) sw = p.swinv[(nb*BN)>>10];
  else                        sw = *p.swinv;
  const int r0 = mb*128;
  const int c0 = nb*BN + wn*((VAR==0)?64:32);
  #pragma unroll
  for(int mf=0;mf<8;mf++){
    #pragma unroll
    for(int j=0;j<4;j++){
      int r = r0 + mf*16 + kq*4 + j;
      float rs = p.rsx[r]*sw;
      #pragma unroll
      for(int nf=0;nf<NF;nf++){
        int c = c0 + nf*16 + lr;
        float val = (float)acc[mf][nf][j]*rs;
        if constexpr (EPI==EPI_IFG){
          int mat = c >> 10;
          p.outb[(size_t)mat*9437184 + (size_t)r*1024 + (c&1023)] = f2bf(val);
        } else if constexpr (EPI==EPI_GLU){
          float v2 = (float)acc2[mf][nf][j]*rs;
          p.outb[(size_t)r*Ncols + c] = f2bf(val*sigm(val)*v2);
        } else if constexpr (EPI==EPI_RESID){
          int b = r >> p.bshift;
          size_t idx = (size_t)r*DM + c;
          p.outf[idx] = p.resid[idx] + p.egate[b*6144 + 5*1024 + c]*val;
        } else { // EPI_OUT
          p.outb[(size_t)r*Ncols + c] = f2bf(val);
        }
      }
    }
  }
}

// ---------------- small split-K int8 GEMM (ctx down-proj), atomic f32 ----------------
__global__ __launch_bounds__(256, 2)
void gemm_ra8(const signed char* __restrict__ Aq, const signed char* __restrict__ Wq,
              int K, int lda, GemmP p){
  __shared__ signed char As[128*128];
  __shared__ signed char Bs[128*128];
  const int tid = threadIdx.x;
  const int wave = tid>>6, lane = tid&63;
  const int nwg = gridDim.x*gridDim.y;
  const int id  = blockIdx.y*gridDim.x + blockIdx.x;
  const int wg  = (id&7)*(nwg>>3) + (id>>3);
  const int nb  = wg % gridDim.x, mb = wg / gridDim.x;
  const int wr = wave>>1, wc = wave&1;
  const int koff = blockIdx.z*K;

  const int grow = wave*8 + (lane>>3);
  const int gcol = (lane&7)*16;
  const signed char* ag = Aq + (size_t)(mb*128 + grow)*lda + koff + gcol;
  const signed char* bg = Wq + (size_t)(nb*128 + grow)*lda + koff + gcol;
  char* asl = (char*)As + wave*1024;
  char* bsl = (char*)Bs + wave*1024;

  i32x4 acc[4][4];
  #pragma unroll
  for(int i=0;i<4;i++)
    #pragma unroll
    for(int j=0;j<4;j++) acc[i][j] = (i32x4){0,0,0,0};

  const int lrow = lane&15, kq = lane>>4;
  const signed char* arow = &As[(wr*64 + lrow)*128 + kq*16];
  const signed char* brow = &Bs[(wc*64 + lrow)*128 + kq*16];

  for(int k0=0; k0<K; k0+=128){
    #pragma unroll
    for(int pp=0;pp<4;pp++){
      gl_lds16(ag + (size_t)pp*32*lda + k0, asl + pp*4096);
      gl_lds16(bg + (size_t)pp*32*lda + k0, bsl + pp*4096);
    }
    __syncthreads();
    #pragma unroll
    for(int kk=0;kk<2;kk++){
      i32x4 af[4], bfr[4];
      #pragma unroll
      for(int m=0;m<4;m++) af[m]  = *(const i32x4*)(arow + m*2048 + kk*64);
      #pragma unroll
      for(int n=0;n<4;n++) bfr[n] = *(const i32x4*)(brow + n*2048 + kk*64);
      #pragma unroll
      for(int m=0;m<4;m++)
        #pragma unroll
        for(int n=0;n<4;n++)
          acc[m][n] = __builtin_amdgcn_mfma_i32_16x16x64_i8(af[m], bfr[n], acc[m][n], 0,0,0);
    }
    __syncthreads();
  }

  const float sw = *p.swinv;
  const int r0 = mb*128 + wr*64, c0 = nb*128 + wc*64;
  #pragma unroll
  for(int m=0;m<4;m++){
    #pragma unroll
    for(int j=0;j<4;j++){
      int r = r0 + m*16 + kq*4 + j;
      float rs = p.rsx[r]*sw;
      #pragma unroll
      for(int n=0;n<4;n++){
        int c = c0 + n*16 + lrow;
        float val = (float)acc[m][n][j]*rs;
        int b = r >> p.bshift;
        size_t idx = (size_t)r*DM + c;
        atomicAdd(&p.outf[idx], p.egate[b*6144 + 5*1024 + c]*val);
      }
    }
  }
}

// ================= host =================
extern "C" void kernel_launch(void* const* d_in, const int* in_sizes, int n_in,
                              void* d_out, int out_size, void* d_ws, size_t ws_size,
                              hipStream_t stream){
  (void)in_sizes; (void)n_in; (void)out_size; (void)ws_size;
  const float* hidden   = (const float*)d_in[0];
  const float* enc      = (const float*)d_in[1];
  const float* temb     = (const float*)d_in[2];
  const float* adaln_w  = (const float*)d_in[3];
  const float* adaln_b  = (const float*)d_in[4];
  const float* adaln_cw = (const float*)d_in[5];
  const float* adaln_cb = (const float*)d_in[6];
  const float* wi  = (const float*)d_in[7];
  const float* wf  = (const float*)d_in[8];
  const float* wg  = (const float*)d_in[9];
  const float* wo  = (const float*)d_in[10];
  const float* gnw = (const float*)d_in[11];
  const float* ffg = (const float*)d_in[12];
  const float* ffd = (const float*)d_in[13];
  const float* fcg = (const float*)d_in[14];
  const float* fcd = (const float*)d_in[15];

  const size_t MB = 1024ull*1024ull;
  char* ws = (char*)d_ws;
  signed char* W8_IFG = (signed char*)(ws + 0*MB);
  signed char* W8_WO  = (signed char*)(ws + 3*MB);
  signed char* W8_FFG = (signed char*)(ws + 4*MB);
  signed char* W8_FFD = (signed char*)(ws + 12*MB);
  signed char* W8_FCG = (signed char*)(ws + 16*MB);
  signed char* W8_FCD = (signed char*)(ws + 24*MB);
  float* PART  = (float*)(ws + 28*MB);
  float* SWINV = (float*)(ws + 28*MB + 32*1024);
  float* EH    = (float*)(ws + 28*MB + 64*1024);
  float* EC    = (float*)(ws + 28*MB + 112*1024);
  float* RSX1  = (float*)(ws + 28*MB + 160*1024);
  float* RSX2  = (float*)(ws + 28*MB + 200*1024);
  float* RSX3  = (float*)(ws + 28*MB + 240*1024);
  float* RSXZ  = (float*)(ws + 28*MB + 280*1024);
  float* RSX4  = (float*)(ws + 28*MB + 320*1024);
  float* RSXZC = (float*)(ws + 28*MB + 328*1024);
  float* SCANA = (float*)(ws + 29*MB);
  float* SCANB = (float*)(ws + 33*MB);
  float* SCANH = (float*)(ws + 37*MB);
  signed char* XQ8 = (signed char*)(ws + 41*MB);
  unsigned short* IRAW = (unsigned short*)(ws + 51*MB);
  unsigned short* FRAW = (unsigned short*)(ws + 69*MB);
  unsigned short* GRAW = (unsigned short*)(ws + 87*MB);
  unsigned short* ATTN = (unsigned short*)(ws + 51*MB);
  signed char* SG8 = (signed char*)(ws + 51*MB);
  float* HNEW = (float*)(ws + 105*MB);
  unsigned short* SGB = (unsigned short*)(ws + 137*MB);
  float* OUT_H = (float*)d_out;
  float* OUT_C = (float*)d_out + 8388608;

  // ---- weight quantization ----
  WList L;
  L.w[0]=wi;  L.n[0]=1048576ull; L.q[0]=W8_IFG;
  L.w[1]=wf;  L.n[1]=1048576ull; L.q[1]=W8_IFG + 1048576;
  L.w[2]=wg;  L.n[2]=1048576ull; L.q[2]=W8_IFG + 2097152;
  L.w[3]=wo;  L.n[3]=1048576ull; L.q[3]=W8_WO;
  L.w[4]=ffg; L.n[4]=8388608ull; L.q[4]=W8_FFG;
  L.w[5]=ffd; L.n[5]=4194304ull; L.q[5]=W8_FFD;
  L.w[6]=fcg; L.n[6]=8388608ull; L.q[6]=W8_FCG;
  L.w[7]=fcd; L.n[7]=4194304ull; L.q[7]=W8_FCD;
  wq_reduce  <<<dim3(512,8), 256, 0, stream>>>(L, PART);
  wq_finalize<<<8,          256, 0, stream>>>(L, PART, SWINV);
  wq_quant   <<<dim3(1024,8),256, 0, stream>>>(L, SWINV);

  // ---- adaLN embeddings (merged) ----
  adaln_gemv2<<<dim3(1536,2,2), 256, 0, stream>>>(temb, adaln_w, adaln_b, EH,
                                                  adaln_cw, adaln_cb, EC);

  // ---- joint modnorm (enc+hidden merged) ----
  modnorm_joint<<<9216, 256, 0, stream>>>(enc, hidden, EC, EH, XQ8, RSX1);

  // ---- merged i/f/g bitlinear (N=3072) ----
  GemmP p{};
  p.rsx = RSX1; p.swinv = SWINV; p.outb = IRAW;
  gemm8<0,EPI_IFG,0><<<dim3(12,72), 256, 0, stream>>>(XQ8, W8_IFG, 3072, 1024, 1024, p);

  // ---- HGRN scan + fused gnorm/quant ----
  scan_pass1<<<dim3(NCH,2), 256, 0, stream>>>(IRAW, FRAW, SCANA, SCANB);
  scan_pass2<<<8,           256, 0, stream>>>(SCANA, SCANB, SCANH);
  scan3_gnorm<<<dim3(NCH,2), 256, 0, stream>>>(IRAW, FRAW, SCANH, GRAW, gnw, XQ8, RSX2);

  // ---- wo bitlinear -> bf16 ATTN ----
  GemmP pw{};
  pw.rsx = RSX2; pw.swinv = SWINV+3; pw.outb = ATTN;
  gemm8<2,EPI_OUT,0><<<dim3(8,72), 256, 0, stream>>>(XQ8, W8_WO, 1024, 1024, 1024, pw);

  // ---- fused residual + LN/mod/rmsnorm/quant (ctx+img merged) ----
  resid_modnorm_joint<<<9216, 256, 0, stream>>>(hidden, enc, ATTN, EH, EC,
                                                HNEW, OUT_C,
                                                XQ8, XQ8 + (size_t)8192*1024,
                                                RSX3, RSX4);

  // ---- image MLP ----
  GemmP pg{};
  pg.rsx = RSX3; pg.swinv = SWINV+4; pg.outb = SGB; pg.w2 = W8_FFG + (size_t)4096*1024;
  gemm8<1,EPI_GLU,1><<<dim3(32,64), 256, 0, stream>>>(XQ8, W8_FFG, 4096, 1024, 1024, pg);
  rmsq4096<<<8192, 256, 0, stream>>>(SGB, SG8, RSXZ);
  GemmP pd{};
  pd.rsx = RSXZ; pd.swinv = SWINV+5; pd.outf = OUT_H; pd.resid = HNEW; pd.egate = EH; pd.bshift = 12;
  gemm8<2,EPI_RESID,0><<<dim3(8,64), 256, 0, stream>>>(SG8, W8_FFD, 1024, 4096, 4096, pd);

  // ---- context MLP ----
  GemmP pc{};
  pc.rsx = RSX4; pc.swinv = SWINV+6; pc.outb = SGB; pc.w2 = W8_FCG + (size_t)4096*1024;
  gemm8<1,EPI_GLU,1><<<dim3(32,8), 256, 0, stream>>>(XQ8 + (size_t)8192*1024, W8_FCG, 4096, 1024, 1024, pc);
  rmsq4096<<<1024, 256, 0, stream>>>(SGB, SG8, RSXZC);
  GemmP pe{};
  pe.rsx = RSXZC; pe.swinv = SWINV+7; pe.outf = OUT_C; pe.egate = EC; pe.bshift = 9;
  gemm_ra8<<<dim3(8,8,4), 256, 0, stream>>>(SG8, W8_FCD, 1024, 4096, pe);
}